// Round 2
// baseline (141.740 us; speedup 1.0000x reference)
//
#include <hip/hip_runtime.h>
#include <math.h>

// VanillaRNN, Wh is (1,H) => scalar recurrence per batch element:
//   s_{t+1} = G(u_t, s_t),  G(u,s) = bh + sum_j wh_j*tanh(wx_j*u + bx_j + s)
// R11: speculative-address decoupling inside k_scan_seg.
//  The serial wall is 256 x L_step (pure latency; parallelism cannot help).
//  R10's L_step ~407cy = addr chain (~40) + 4x ds_read_b128 (~180) + combine
//  (~40) + overhead. R11 splits the recurrence into two chains:
//   - FAST chain zf (critical): cubic-in-u, LINEAR-in-z from center rows
//     q1,q2 only -> drives the next step's LDS address. Depth ~9 ops + LDS.
//     Waits only on the first two ds_reads (counted lgkmcnt).
//   - ACCURATE chain za (lagging, off-critical): exact R10 math; Lagrange
//     weights from za computed during the LDS wait; full cubic combine after
//     q0..q3 land. Depth ~8 ops << L_step, never the wall.
//  zf resyncs to za every 8-step chunk => |zf-za| << 0.5, so the stencil is
//  identical to R10's in essentially every step (off-by-one near cell edges
//  changes the interpolant by ~1e-6, far under the 2.5e-4 combine budget).
//  Everything outside k_scan_seg's step body is unchanged.

#define SEQ   512
#define BATCH 4096
#define HID   2048
#define NOUT  10
#define KPL   32
#define NS    560           // s-grid rows over [-10,10]
#define ROWQ  9             // float4s per s-row (8 u-cells + 1 pad)

#define S_LOc   (-10.0f)
#define S_H     (20.0f / 559.0f)
#define S_INVH  (559.0f / 20.0f)
#define S_BIAS  (10.0f * S_INVH)
#define NSM1F   559.0f
#define U_SCALE (8.0f / 14.0f)
#define U_BIAS  4.0f
#define UCMAXF  7.99951f

#define TABLE_FLOATS (NS * ROWQ * 4)       // 20160 floats (in d_out scratch)
#define WSA_FLOATS (4096 + 14 * 4096)
#define WSB_FLOATS (4096 + 4 * 4096)
#define DZ14 43.0f          // 559/13 node spacing (z-units), exact
#define DZ9  69.875f        // 559/8, exact

__device__ __forceinline__ float fast_exp2(float v) { return __builtin_amdgcn_exp2f(v); }
__device__ __forceinline__ float fast_rcp(float v)  { return __builtin_amdgcn_rcpf(v); }
__device__ __forceinline__ float med3(float a, float lo, float hi) {
    return __builtin_amdgcn_fmed3f(a, lo, hi);
}
__device__ __forceinline__ float fast_tanh(float a) {
    const float C = 2.8853900817779268f;  // 2*log2(e)
    return __builtin_fmaf(-2.0f, fast_rcp(fast_exp2(C * a) + 1.0f), 1.0f);
}
__device__ __forceinline__ float wave_sum(float v) {
#pragma unroll
    for (int m = 1; m < 64; m <<= 1) v += __shfl_xor(v, m, 64);
    return v;
}
// piecewise-cubic Lagrange combine: z' = Phi(z255) from nn node values
__device__ __forceinline__ float combine_eval(float z255, int nn, float dz,
                                              const float* baseA, const float* baseB,
                                              int split, int b) {
    float p = z255 / dz;                               // [0, nn-1]
    int   c = min(max((int)floorf(p) - 1, 0), nn - 4);
    float t = p - (float)c;
    float a0 = t, a1 = t - 1.0f, a2 = t - 2.0f, a3 = t - 3.0f;
    float m01 = a0 * a1, m23 = a2 * a3;
    float w0 = a1 * m23 * (-1.0f / 6.0f), w1 = a0 * m23 * 0.5f;
    float w2 = m01 * a3 * (-0.5f),        w3 = m01 * a2 * (1.0f / 6.0f);
    float y[4];
#pragma unroll
    for (int i = 0; i < 4; ++i) {
        int n = c + i;
        const float* ptr = (n < split) ? (baseA + (size_t)n * 4096)
                                       : (baseB + (size_t)(n - split) * 4096);
        y[i] = ptr[b];
    }
    return __builtin_fmaf(w0, y[0], w1 * y[1]) + __builtin_fmaf(w2, y[2], w3 * y[3]);
}

// ---------------- K1: coefficient table (560 s-rows x 8 u-cells) -> d_out ----------------
__global__ __launch_bounds__(256) void k_coef(const float* __restrict__ Wx, const float* __restrict__ bx,
                                              const float* __restrict__ Wh, const float* __restrict__ bh,
                                              float* __restrict__ tab_g) {
    __shared__ float red[256];
    __shared__ float Gn[32];
    const int k    = blockIdx.x;
    const int node = threadIdx.x & 31;           // 8 cells x 4 Chebyshev nodes
    const int jc   = threadIdx.x >> 5;           // 8 j-chunks of 256
    const int cell = node >> 2, nn = node & 3;
    const float sn = S_LOc + (float)k * S_H;
    const float xi_n = (nn == 0) ? 0.923879533f : (nn == 1) ? 0.382683432f
                     : (nn == 2) ? -0.382683432f : -0.923879533f;
    const float un = (-7.0f + ((float)cell + 0.5f) * 1.75f) + 0.875f * xi_n;
    float p = 0.0f;
    const int j0 = jc * 256;
#pragma unroll 4
    for (int j = j0; j < j0 + 256; ++j)
        p += Wh[j] * fast_tanh(__builtin_fmaf(Wx[j], un, bx[j] + sn));
    red[threadIdx.x] = p;
    __syncthreads();
    if (threadIdx.x < 32) {
        float V = bh[0];
#pragma unroll
        for (int c = 0; c < 8; ++c) V += red[threadIdx.x + 32 * c];
        Gn[threadIdx.x] = __builtin_fmaf(V, S_INVH, S_BIAS);   // normalized next-z
    }
    __syncthreads();
    float4* wq = (float4*)tab_g;
    if (threadIdx.x < 8) {
        const int c = threadIdx.x;
        float G0 = Gn[4*c+0], G1 = Gn[4*c+1], G2 = Gn[4*c+2], G3 = Gn[4*c+3];
        float d03 = G0 - G3, d12 = G1 - G2;
        float a0 = 0.25f * (G0 + G1 + G2 + G3);
        float a1 = 0.5f * (0.923879533f * d03 + 0.382683432f * d12);
        float a2 = 0.5f * 0.707106781f * (G0 - G1 - G2 + G3);
        float a3 = 0.5f * (0.382683432f * d03 - 0.923879533f * d12);
        wq[k * ROWQ + c] = make_float4(a0 - a2, a1 - 3.0f * a3, 2.0f * a2, 4.0f * a3);
    } else if (threadIdx.x == 8) {
        wq[k * ROWQ + 8] = make_float4(0.f, 0.f, 0.f, 0.f);    // pad (never read)
    }
}

// ---------------- K2: 2-segment scan (4 waves/CU, 1 block/CU) ----------------
// blk<16: seg0 (t=0..254 from true init) -> z255 = ws[0..4096)
// else:   seg1 (t=255..510 from node state node*dz) -> node buf (split A/B)
__global__ __launch_bounds__(256) void k_scan_seg(const float* __restrict__ x,
                                                  const float* __restrict__ bh,
                                                  const float* __restrict__ tab_g,
                                                  float* __restrict__ z255,
                                                  float* __restrict__ baseA,
                                                  float* __restrict__ baseB,
                                                  int split, float dz) {
    __shared__ float4 tabs[5200];                // 83200 B -> pins 1 block/CU
    {
        const float4* src = (const float4*)tab_g;
        for (int i = threadIdx.x; i < NS * ROWQ; i += 256) tabs[i] = src[i];
    }
    __syncthreads();
    const char* tabc = (const char*)tabs;
    const int blk = blockIdx.x;
    const int seg  = (blk < 16) ? 0 : 1;
    const int node = seg ? (blk - 16) >> 4 : 0;
    const int eb   = seg ? (blk - 16) & 15 : blk;
    const int b    = eb * 256 + threadIdx.x;

    const int t0     = seg ? 255 : 0;
    const int nsteps = seg ? 256 : 255;

    float za = seg ? (float)node * dz
                   : med3(__builtin_fmaf(bh[0], S_INVH, S_BIAS), 0.0f, NSM1F);
    float zf = za;                               // speculative (address) state

    // Fast/accurate coupled step. cib = ci*16 - 144 (byte offset, off-chain).
    // Critical chain: zf -> med3 -> cvt -> *144 -> +cib -> ds_read(q1,q2)
    //                 -> estrin(r1),estrin(r2) -> sub -> fma -> zf
    auto stepF = [&](float xi, float xi2, int cib) {
        float m  = med3(zf, 1.0f, 557.0f);
        int   km = (int)m;                       // stencil center+1, [1,557]
        const float4* qp = (const float4*)(tabc + (km * 144 + cib));
        float4 q1 = qp[ROWQ];                    // rows km, km+1 first (fast path)
        float4 q2 = qp[2 * ROWQ];
        float4 q0 = qp[0];
        float4 q3 = qp[3 * ROWQ];
        // ---- off-chain work under the LDS wait ----
        float kmf = (float)km;                   // cvt back
        float tf  = zf - kmf;                    // = ts_f - 1
        float e   = med3(za, 0.0f, NSM1F) - kmf; // = ts_a - 1 (accurate)
        float c0 = e + 1.0f, c1 = e, c2 = e - 1.0f, c3 = e - 2.0f;
        float n01 = c0 * c1, n23 = c2 * c3;
        float ws0 = c1 * n23 * (-1.0f / 6.0f), ws1 = c0 * n23 * 0.5f;
        float ws2 = n01 * c3 * (-0.5f),        ws3 = n01 * c2 * (1.0f / 6.0f);
        // ---- fast combine (critical; waits only q1,q2) ----
        float l1 = __builtin_fmaf(q1.y, xi, q1.x), h1 = __builtin_fmaf(q1.w, xi, q1.z);
        float l2 = __builtin_fmaf(q2.y, xi, q2.x), h2 = __builtin_fmaf(q2.w, xi, q2.z);
        float r1 = __builtin_fmaf(h1, xi2, l1);
        float r2 = __builtin_fmaf(h2, xi2, l2);
        zf = __builtin_fmaf(tf, r2 - r1, r1);    // linear-in-z estimate
        // ---- accurate combine (lagging chain) ----
        float l0 = __builtin_fmaf(q0.y, xi, q0.x), h0 = __builtin_fmaf(q0.w, xi, q0.z);
        float l3 = __builtin_fmaf(q3.y, xi, q3.x), h3 = __builtin_fmaf(q3.w, xi, q3.z);
        float r0 = __builtin_fmaf(h0, xi2, l0);
        float r3 = __builtin_fmaf(h3, xi2, l3);
        za = __builtin_fmaf(ws0, r0, ws1 * r1) + __builtin_fmaf(ws2, r2, ws3 * r3);
    };

    // accurate-only step (tail; address from za)
    auto stepA = [&](float xi, float xi2, int cib) {
        float m  = med3(za, 1.0f, 557.0f);
        int   km = (int)m;
        const float4* qp = (const float4*)(tabc + (km * 144 + cib));
        float4 q0 = qp[0];
        float4 q1 = qp[ROWQ];
        float4 q2 = qp[2 * ROWQ];
        float4 q3 = qp[3 * ROWQ];
        float kmf = (float)km;
        float e   = med3(za, 0.0f, NSM1F) - kmf;
        float c0 = e + 1.0f, c1 = e, c2 = e - 1.0f, c3 = e - 2.0f;
        float n01 = c0 * c1, n23 = c2 * c3;
        float ws0 = c1 * n23 * (-1.0f / 6.0f), ws1 = c0 * n23 * 0.5f;
        float ws2 = n01 * c3 * (-0.5f),        ws3 = n01 * c2 * (1.0f / 6.0f);
        float l0 = __builtin_fmaf(q0.y, xi, q0.x), h0 = __builtin_fmaf(q0.w, xi, q0.z);
        float l1 = __builtin_fmaf(q1.y, xi, q1.x), h1 = __builtin_fmaf(q1.w, xi, q1.z);
        float l2 = __builtin_fmaf(q2.y, xi, q2.x), h2 = __builtin_fmaf(q2.w, xi, q2.z);
        float l3 = __builtin_fmaf(q3.y, xi, q3.x), h3 = __builtin_fmaf(q3.w, xi, q3.z);
        float r0 = __builtin_fmaf(h0, xi2, l0);
        float r1 = __builtin_fmaf(h1, xi2, l1);
        float r2 = __builtin_fmaf(h2, xi2, l2);
        float r3 = __builtin_fmaf(h3, xi2, l3);
        za = __builtin_fmaf(ws0, r0, ws1 * r1) + __builtin_fmaf(ws2, r2, ws3 * r3);
    };

    float cur[8], nxt[8];
#pragma unroll
    for (int i = 0; i < 8; ++i)
        cur[i] = x[(size_t)min(t0 + i, SEQ - 1) * BATCH + b];

    const int full = nsteps >> 3, tail = nsteps & 7;
    for (int c = 0; c < full; ++c) {
        const int nb = t0 + (c + 1) * 8;
#pragma unroll
        for (int i = 0; i < 8; ++i)
            nxt[i] = x[(size_t)min(nb + i, SEQ - 1) * BATCH + b];
        // u-only prep for all 8 steps, off the z-chain
        float xiA[8], xi2A[8]; int cibA[8];
#pragma unroll
        for (int i = 0; i < 8; ++i) {
            float uc = med3(__builtin_fmaf(cur[i], U_SCALE, U_BIAS), 0.0f, UCMAXF);
            int   ci = (int)uc;                  // trunc == floor (uc >= 0)
            float xi = __builtin_fmaf(2.0f, uc - (float)ci, -1.0f);
            xiA[i] = xi; xi2A[i] = xi * xi; cibA[i] = (ci << 4) - 144;
        }
#pragma unroll
        for (int i = 0; i < 8; ++i) stepF(xiA[i], xi2A[i], cibA[i]);
        zf = za;                                 // resync estimate to accurate
#pragma unroll
        for (int i = 0; i < 8; ++i) cur[i] = nxt[i];
    }
    for (int i = 0; i < tail; ++i) {             // wave-uniform tail (<=7)
        float uc = med3(__builtin_fmaf(cur[i], U_SCALE, U_BIAS), 0.0f, UCMAXF);
        int   ci = (int)uc;
        float xi = __builtin_fmaf(2.0f, uc - (float)ci, -1.0f);
        stepA(xi, xi * xi, (ci << 4) - 144);
    }

    const float z = za;
    if (seg == 0) z255[b] = z;
    else {
        float* p = (node < split) ? (baseA + (size_t)node * 4096)
                                  : (baseB + (size_t)(node - split) * 4096);
        p[b] = z;
    }
}

// ---------------- Tier B combine: drain node bufs (d_out+ws) -> s in ws ----------------
__global__ __launch_bounds__(256) void k_combine(const float* __restrict__ baseA,
                                                 const float* __restrict__ baseB,
                                                 int split, int nn, float dz,
                                                 float* __restrict__ zs) {
    const int b = blockIdx.x * 256 + threadIdx.x;
    float zz = combine_eval(zs[b], nn, dz, baseA, baseB, split, b);
    zs[b] = __builtin_fmaf(zz, S_H, S_LOc);          // denormalized s_511
}

// ---------------- Tier A: fused combine (all node bufs in ws) + head ----------------
__global__ __launch_bounds__(256) void head_combine_A(
    const float* __restrict__ x,  const float* __restrict__ Wx,
    const float* __restrict__ bx, const float* __restrict__ Wy,
    const float* __restrict__ by, const float* __restrict__ ws,
    float* __restrict__ out)
{
    const int lane = threadIdx.x & 63;
    const int wave = threadIdx.x >> 6;
    const int b    = blockIdx.x * 4 + wave;

    float zz = combine_eval(ws[b], 14, DZ14, ws + 4096, ws + 4096, 14, b);
    const float s = __builtin_fmaf(zz, S_H, S_LOc);

    const float C  = 2.8853900817779268f;
    const float u  = x[(size_t)(SEQ - 1) * BATCH + b];
    const float sc = s * C;
    float acc[NOUT];
#pragma unroll
    for (int i = 0; i < NOUT; ++i) acc[i] = 0.0f;
#pragma unroll 4
    for (int k = 0; k < KPL; ++k) {
        const int j = k * 64 + lane;
        float arg = __builtin_fmaf(u, Wx[j] * C, bx[j] * C) + sc;
        float r   = fast_rcp(fast_exp2(arg) + 1.0f);
        float th  = __builtin_fmaf(-2.0f, r, 1.0f);
#pragma unroll
        for (int i = 0; i < NOUT; ++i)
            acc[i] = __builtin_fmaf(Wy[i * HID + j], th, acc[i]);
    }
#pragma unroll
    for (int i = 0; i < NOUT; ++i) acc[i] = wave_sum(acc[i]) + by[i];
    float m = acc[0];
#pragma unroll
    for (int i = 1; i < NOUT; ++i) m = fmaxf(m, acc[i]);
    const float L2E = 1.4426950408889634f;
    float ev[NOUT]; float Z = 0.0f;
#pragma unroll
    for (int i = 0; i < NOUT; ++i) { ev[i] = fast_exp2((acc[i] - m) * L2E); Z += ev[i]; }
    const float rz = fast_rcp(Z);
    if (lane == 0) {
#pragma unroll
        for (int i = 0; i < NOUT; ++i) out[(size_t)b * NOUT + i] = ev[i] * rz;
    }
}

// ---------------- exact scan + head (validated R0; also tier-B head) ----------------
__global__ __launch_bounds__(256) void rnn_scan_exact(
    const float* __restrict__ x,  const float* __restrict__ Wx,
    const float* __restrict__ bx, const float* __restrict__ Wh,
    const float* __restrict__ bh, float* __restrict__ s_out)
{
    const int lane = threadIdx.x & 63;
    const int wave = threadIdx.x >> 6;
    const int b    = blockIdx.x * 4 + wave;
    const float C = 2.8853900817779268f;
    float wxs[KPL], bxs[KPL], whn[KPL];
    float swh = 0.0f;
#pragma unroll
    for (int k = 0; k < KPL; ++k) {
        const int j = k * 64 + lane;
        const float w = Wh[j];
        wxs[k] = Wx[j] * C; bxs[k] = bx[j] * C; whn[k] = -2.0f * w; swh += w;
    }
    swh = wave_sum(swh);
    const float bh0 = bh[0];
    const float K0  = bh0 + swh;
    float s = bh0, u = x[b];
    for (int t = 0; t < SEQ - 1; ++t) {
        float u_next = x[(size_t)(t + 1) * BATCH + b];
        const float sc = s * C;
        float p = 0.0f;
#pragma unroll
        for (int k = 0; k < KPL; ++k) {
            float arg = __builtin_fmaf(u, wxs[k], bxs[k]) + sc;
            float r   = fast_rcp(fast_exp2(arg) + 1.0f);
            p = __builtin_fmaf(whn[k], r, p);
        }
        s = K0 + wave_sum(p);
        u = u_next;
    }
    if (lane == 0) s_out[b] = s;
}

__global__ __launch_bounds__(256) void rnn_head_exact(
    const float* __restrict__ x,  const float* __restrict__ Wx,
    const float* __restrict__ bx, const float* __restrict__ Wy,
    const float* __restrict__ by, const float* __restrict__ s_in,
    float* __restrict__ out)
{
    const int lane = threadIdx.x & 63;
    const int wave = threadIdx.x >> 6;
    const int b    = blockIdx.x * 4 + wave;
    const float C  = 2.8853900817779268f;
    const float s  = s_in[b];
    const float u  = x[(size_t)(SEQ - 1) * BATCH + b];
    const float sc = s * C;
    float acc[NOUT];
#pragma unroll
    for (int i = 0; i < NOUT; ++i) acc[i] = 0.0f;
#pragma unroll 4
    for (int k = 0; k < KPL; ++k) {
        const int j = k * 64 + lane;
        float arg = __builtin_fmaf(u, Wx[j] * C, bx[j] * C) + sc;
        float r   = fast_rcp(fast_exp2(arg) + 1.0f);
        float th  = __builtin_fmaf(-2.0f, r, 1.0f);
#pragma unroll
        for (int i = 0; i < NOUT; ++i)
            acc[i] = __builtin_fmaf(Wy[i * HID + j], th, acc[i]);
    }
#pragma unroll
    for (int i = 0; i < NOUT; ++i) acc[i] = wave_sum(acc[i]) + by[i];
    float m = acc[0];
#pragma unroll
    for (int i = 1; i < NOUT; ++i) m = fmaxf(m, acc[i]);
    const float L2E = 1.4426950408889634f;
    float ev[NOUT]; float Z = 0.0f;
#pragma unroll
    for (int i = 0; i < NOUT; ++i) { ev[i] = fast_exp2((acc[i] - m) * L2E); Z += ev[i]; }
    const float rz = fast_rcp(Z);
    if (lane == 0) {
#pragma unroll
        for (int i = 0; i < NOUT; ++i) out[(size_t)b * NOUT + i] = ev[i] * rz;
    }
}

extern "C" void kernel_launch(void* const* d_in, const int* in_sizes, int n_in,
                              void* d_out, int out_size, void* d_ws, size_t ws_size,
                              hipStream_t stream)
{
    const float* x  = (const float*)d_in[0];
    const float* Wx = (const float*)d_in[1];
    const float* bx = (const float*)d_in[2];
    const float* Wh = (const float*)d_in[3];
    const float* bh = (const float*)d_in[4];
    const float* Wy = (const float*)d_in[5];
    const float* by = (const float*)d_in[6];
    float* out = (float*)d_out;
    float* wf  = (float*)d_ws;

    if (ws_size >= (size_t)WSA_FLOATS * sizeof(float)) {
        // Tier A: 14 nodes, all node bufs in ws; 3 launches
        k_coef<<<NS, 256, 0, stream>>>(Wx, bx, Wh, bh, out);
        k_scan_seg<<<16 + 14 * 16, 256, 0, stream>>>(x, bh, out, wf,
                                                     wf + 4096, wf + 4096, 14, DZ14);
        head_combine_A<<<BATCH / 4, 256, 0, stream>>>(x, Wx, bx, Wy, by, wf, out);
    } else if (ws_size >= (size_t)WSB_FLOATS * sizeof(float)) {
        // Tier B: 9 nodes (5 bufs borrow d_out, drained by k_combine before head)
        k_coef<<<NS, 256, 0, stream>>>(Wx, bx, Wh, bh, out);
        k_scan_seg<<<16 + 9 * 16, 256, 0, stream>>>(x, bh, out, wf,
                                                    out + TABLE_FLOATS, wf + 4096, 5, DZ9);
        k_combine<<<16, 256, 0, stream>>>(out + TABLE_FLOATS, wf + 4096, 5, 9, DZ9, wf);
        rnn_head_exact<<<BATCH / 4, 256, 0, stream>>>(x, Wx, bx, Wy, by, wf, out);
    } else {
        rnn_scan_exact<<<BATCH / 4, 256, 0, stream>>>(x, Wx, bx, Wh, bh, wf);
        rnn_head_exact<<<BATCH / 4, 256, 0, stream>>>(x, Wx, bx, Wy, by, wf, out);
    }
}

// Round 3
// 141.299 us; speedup vs baseline: 1.0031x; 1.0031x over previous
//
#include <hip/hip_runtime.h>
#include <math.h>

// VanillaRNN, Wh is (1,H) => scalar recurrence per batch element:
//   s_{t+1} = G(u_t, s_t),  G(u,s) = bh + sum_j wh_j*tanh(wx_j*u + bx_j + s)
// R12: software-pipelined scan step with explicit counted lgkmcnt (inline asm).
//  R11 post-mortem: the accurate combine's lgkmcnt(0) sat between step k's
//  reads and step k+1's reads in program order -> full LDS drain every step
//  (absmax bit-identical to R10 proved the zf math was fine; the schedule
//  wasn't). R12 delays the accurate combine by ONE step so it executes inside
//  the next step's LDS shadow:
//   iter k: addr(zf_k); issue q_k (q1,q2,q0,q3);
//           lgkmcnt(4)  -> q_{k-1} landed; compute za_{k-1} (off-chain);
//           lgkmcnt(2)  -> q1_k,q2_k landed; zf_{k+1} = r1 + tf*(r2-r1).
//  Counted waits are exact: only these asm ds_reads touch lgkmcnt in-loop
//  (x loads are vmcnt; staging drained by __syncthreads). Each waitcnt is
//  followed by sched_barrier(0) per the hoist-past-asm-waitcnt hazard.
//  za math identical to R10/R11 (same stencil/weights); zf drift bounded by
//  contraction (tf clamped as insurance). Everything else unchanged.

#define SEQ   512
#define BATCH 4096
#define HID   2048
#define NOUT  10
#define KPL   32
#define NS    560           // s-grid rows over [-10,10]
#define ROWQ  9             // float4s per s-row (8 u-cells + 1 pad)

#define S_LOc   (-10.0f)
#define S_H     (20.0f / 559.0f)
#define S_INVH  (559.0f / 20.0f)
#define S_BIAS  (10.0f * S_INVH)
#define NSM1F   559.0f
#define U_SCALE (8.0f / 14.0f)
#define U_BIAS  4.0f
#define UCMAXF  7.99951f

#define TABLE_FLOATS (NS * ROWQ * 4)       // 20160 floats (in d_out scratch)
#define WSA_FLOATS (4096 + 14 * 4096)
#define WSB_FLOATS (4096 + 4 * 4096)
#define DZ14 43.0f          // 559/13 node spacing (z-units), exact
#define DZ9  69.875f        // 559/8, exact

typedef float f32x4 __attribute__((ext_vector_type(4)));

__device__ __forceinline__ float fast_exp2(float v) { return __builtin_amdgcn_exp2f(v); }
__device__ __forceinline__ float fast_rcp(float v)  { return __builtin_amdgcn_rcpf(v); }
__device__ __forceinline__ float med3(float a, float lo, float hi) {
    return __builtin_amdgcn_fmed3f(a, lo, hi);
}
__device__ __forceinline__ float fast_tanh(float a) {
    const float C = 2.8853900817779268f;  // 2*log2(e)
    return __builtin_fmaf(-2.0f, fast_rcp(fast_exp2(C * a) + 1.0f), 1.0f);
}
__device__ __forceinline__ float wave_sum(float v) {
#pragma unroll
    for (int m = 1; m < 64; m <<= 1) v += __shfl_xor(v, m, 64);
    return v;
}
// piecewise-cubic Lagrange combine: z' = Phi(z255) from nn node values
__device__ __forceinline__ float combine_eval(float z255, int nn, float dz,
                                              const float* baseA, const float* baseB,
                                              int split, int b) {
    float p = z255 / dz;                               // [0, nn-1]
    int   c = min(max((int)floorf(p) - 1, 0), nn - 4);
    float t = p - (float)c;
    float a0 = t, a1 = t - 1.0f, a2 = t - 2.0f, a3 = t - 3.0f;
    float m01 = a0 * a1, m23 = a2 * a3;
    float w0 = a1 * m23 * (-1.0f / 6.0f), w1 = a0 * m23 * 0.5f;
    float w2 = m01 * a3 * (-0.5f),        w3 = m01 * a2 * (1.0f / 6.0f);
    float y[4];
#pragma unroll
    for (int i = 0; i < 4; ++i) {
        int n = c + i;
        const float* ptr = (n < split) ? (baseA + (size_t)n * 4096)
                                       : (baseB + (size_t)(n - split) * 4096);
        y[i] = ptr[b];
    }
    return __builtin_fmaf(w0, y[0], w1 * y[1]) + __builtin_fmaf(w2, y[2], w3 * y[3]);
}

// ---------------- K1: coefficient table (560 s-rows x 8 u-cells) -> d_out ----------------
__global__ __launch_bounds__(256) void k_coef(const float* __restrict__ Wx, const float* __restrict__ bx,
                                              const float* __restrict__ Wh, const float* __restrict__ bh,
                                              float* __restrict__ tab_g) {
    __shared__ float red[256];
    __shared__ float Gn[32];
    const int k    = blockIdx.x;
    const int node = threadIdx.x & 31;           // 8 cells x 4 Chebyshev nodes
    const int jc   = threadIdx.x >> 5;           // 8 j-chunks of 256
    const int cell = node >> 2, nn = node & 3;
    const float sn = S_LOc + (float)k * S_H;
    const float xi_n = (nn == 0) ? 0.923879533f : (nn == 1) ? 0.382683432f
                     : (nn == 2) ? -0.382683432f : -0.923879533f;
    const float un = (-7.0f + ((float)cell + 0.5f) * 1.75f) + 0.875f * xi_n;
    float p = 0.0f;
    const int j0 = jc * 256;
#pragma unroll 4
    for (int j = j0; j < j0 + 256; ++j)
        p += Wh[j] * fast_tanh(__builtin_fmaf(Wx[j], un, bx[j] + sn));
    red[threadIdx.x] = p;
    __syncthreads();
    if (threadIdx.x < 32) {
        float V = bh[0];
#pragma unroll
        for (int c = 0; c < 8; ++c) V += red[threadIdx.x + 32 * c];
        Gn[threadIdx.x] = __builtin_fmaf(V, S_INVH, S_BIAS);   // normalized next-z
    }
    __syncthreads();
    float4* wq = (float4*)tab_g;
    if (threadIdx.x < 8) {
        const int c = threadIdx.x;
        float G0 = Gn[4*c+0], G1 = Gn[4*c+1], G2 = Gn[4*c+2], G3 = Gn[4*c+3];
        float d03 = G0 - G3, d12 = G1 - G2;
        float a0 = 0.25f * (G0 + G1 + G2 + G3);
        float a1 = 0.5f * (0.923879533f * d03 + 0.382683432f * d12);
        float a2 = 0.5f * 0.707106781f * (G0 - G1 - G2 + G3);
        float a3 = 0.5f * (0.382683432f * d03 - 0.923879533f * d12);
        wq[k * ROWQ + c] = make_float4(a0 - a2, a1 - 3.0f * a3, 2.0f * a2, 4.0f * a3);
    } else if (threadIdx.x == 8) {
        wq[k * ROWQ + 8] = make_float4(0.f, 0.f, 0.f, 0.f);    // pad (never read)
    }
}

// ---------------- K2: 2-segment scan (4 waves/CU, 1 block/CU) ----------------
// blk<16: seg0 (t=0..254 from true init) -> z255 = ws[0..4096)
// else:   seg1 (t=255..510 from node state node*dz) -> node buf (split A/B)

// One pipelined step. FIRST=1 only for global step 0 (no q_prev yet).
// Program order: addr -> issue reads -> [lgkmcnt(4); za_{k-1}] -> lgkmcnt(2)
//                -> zf update -> rotate prev.
#define STEP_BODY(xi_, xi2_, cib_, FIRST)                                      \
{                                                                              \
    float m_   = med3(zf, 1.0f, 557.0f);                                       \
    int   km_  = (int)m_;                                                      \
    float kmf_ = (float)km_;                                                   \
    float tf_  = med3(zf - kmf_, -1.0f, 2.0f);                                 \
    int   ab_  = km_ * 144 + (cib_);                                           \
    f32x4 q0_, q1_, q2_, q3_;                                                  \
    asm volatile("ds_read_b128 %0, %4 offset:144\n\t"                          \
                 "ds_read_b128 %1, %4 offset:288\n\t"                          \
                 "ds_read_b128 %2, %4 offset:0\n\t"                            \
                 "ds_read_b128 %3, %4 offset:432"                              \
                 : "=v"(q1_), "=v"(q2_), "=v"(q0_), "=v"(q3_)                  \
                 : "v"(ab_) : "memory");                                       \
    if (!(FIRST)) {                                                            \
        asm volatile("s_waitcnt lgkmcnt(4)" ::: "memory");                     \
        __builtin_amdgcn_sched_barrier(0);                                     \
        float e_  = med3(za, 0.0f, NSM1F) - kmfp;                              \
        float c0_ = e_ + 1.0f, c1_ = e_, c2_ = e_ - 1.0f, c3_ = e_ - 2.0f;     \
        float n01_ = c0_ * c1_, n23_ = c2_ * c3_;                              \
        float w0_ = c1_ * n23_ * (-1.0f / 6.0f), w1_ = c0_ * n23_ * 0.5f;      \
        float w2_ = n01_ * c3_ * (-0.5f),        w3_ = n01_ * c2_ * (1.0f/6.0f);\
        float l0_ = __builtin_fmaf(p0[1], xip, p0[0]);                         \
        float h0_ = __builtin_fmaf(p0[3], xip, p0[2]);                         \
        float l3_ = __builtin_fmaf(p3[1], xip, p3[0]);                         \
        float h3_ = __builtin_fmaf(p3[3], xip, p3[2]);                         \
        float r0_ = __builtin_fmaf(h0_, xi2p, l0_);                            \
        float r3_ = __builtin_fmaf(h3_, xi2p, l3_);                            \
        za = __builtin_fmaf(w0_, r0_, w1_ * r1p)                               \
           + __builtin_fmaf(w2_, r2p, w3_ * r3_);                              \
    }                                                                          \
    asm volatile("s_waitcnt lgkmcnt(2)" ::: "memory");                         \
    __builtin_amdgcn_sched_barrier(0);                                         \
    float l1_ = __builtin_fmaf(q1_[1], (xi_), q1_[0]);                         \
    float h1_ = __builtin_fmaf(q1_[3], (xi_), q1_[2]);                         \
    float l2_ = __builtin_fmaf(q2_[1], (xi_), q2_[0]);                         \
    float h2_ = __builtin_fmaf(q2_[3], (xi_), q2_[2]);                         \
    float r1_ = __builtin_fmaf(h1_, (xi2_), l1_);                              \
    float r2_ = __builtin_fmaf(h2_, (xi2_), l2_);                              \
    zf = __builtin_fmaf(tf_, r2_ - r1_, r1_);                                  \
    p0 = q0_; p3 = q3_;                                                        \
    xip = (xi_); xi2p = (xi2_); kmfp = kmf_; r1p = r1_; r2p = r2_;             \
}

__global__ __launch_bounds__(256) void k_scan_seg(const float* __restrict__ x,
                                                  const float* __restrict__ bh,
                                                  const float* __restrict__ tab_g,
                                                  float* __restrict__ z255,
                                                  float* __restrict__ baseA,
                                                  float* __restrict__ baseB,
                                                  int split, float dz) {
    __shared__ float4 tabs[5200];                // 83200 B -> pins 1 block/CU
    {
        const float4* src = (const float4*)tab_g;
        for (int i = threadIdx.x; i < NS * ROWQ; i += 256) tabs[i] = src[i];
    }
    __syncthreads();
    const int tb = (int)(size_t)(&tabs[0]);      // LDS byte base of table
    const int blk = blockIdx.x;
    const int seg  = (blk < 16) ? 0 : 1;
    const int node = seg ? (blk - 16) >> 4 : 0;
    const int eb   = seg ? (blk - 16) & 15 : blk;
    const int b    = eb * 256 + threadIdx.x;

    const int t0     = seg ? 255 : 0;
    const int nsteps = seg ? 256 : 255;

    float za = seg ? (float)node * dz
                   : med3(__builtin_fmaf(bh[0], S_INVH, S_BIAS), 0.0f, NSM1F);
    float zf = za;                               // speculative (address) state

    // pipeline registers (q_prev rows 0/3, prev xi, prev stencil, prev r1/r2)
    f32x4 p0, p3;
    float xip = 0.0f, xi2p = 0.0f, kmfp = 0.0f, r1p = 0.0f, r2p = 0.0f;

    float cur[8], nxt[8];
#pragma unroll
    for (int i = 0; i < 8; ++i)
        cur[i] = x[(size_t)min(t0 + i, SEQ - 1) * BATCH + b];

    const int full = nsteps >> 3, tail = nsteps & 7;

    float xiA[8], xi2A[8]; int cibA[8];
    // ---- chunk 0 (step 0 peeled as FIRST) ----
    {
#pragma unroll
        for (int i = 0; i < 8; ++i)
            nxt[i] = x[(size_t)min(t0 + 8 + i, SEQ - 1) * BATCH + b];
#pragma unroll
        for (int i = 0; i < 8; ++i) {
            float uc = med3(__builtin_fmaf(cur[i], U_SCALE, U_BIAS), 0.0f, UCMAXF);
            int   ci = (int)uc;
            float xi = __builtin_fmaf(2.0f, uc - (float)ci, -1.0f);
            xiA[i] = xi; xi2A[i] = xi * xi; cibA[i] = tb + (ci << 4) - 144;
        }
        STEP_BODY(xiA[0], xi2A[0], cibA[0], 1);
#pragma unroll
        for (int i = 1; i < 8; ++i) STEP_BODY(xiA[i], xi2A[i], cibA[i], 0);
#pragma unroll
        for (int i = 0; i < 8; ++i) cur[i] = nxt[i];
    }
    // ---- chunks 1..full-1 ----
    for (int c = 1; c < full; ++c) {
        const int nb = t0 + (c + 1) * 8;
#pragma unroll
        for (int i = 0; i < 8; ++i)
            nxt[i] = x[(size_t)min(nb + i, SEQ - 1) * BATCH + b];
#pragma unroll
        for (int i = 0; i < 8; ++i) {
            float uc = med3(__builtin_fmaf(cur[i], U_SCALE, U_BIAS), 0.0f, UCMAXF);
            int   ci = (int)uc;
            float xi = __builtin_fmaf(2.0f, uc - (float)ci, -1.0f);
            xiA[i] = xi; xi2A[i] = xi * xi; cibA[i] = tb + (ci << 4) - 144;
        }
#pragma unroll
        for (int i = 0; i < 8; ++i) STEP_BODY(xiA[i], xi2A[i], cibA[i], 0);
#pragma unroll
        for (int i = 0; i < 8; ++i) cur[i] = nxt[i];
    }
    // ---- tail (<=7 steps, wave-uniform) ----
    for (int i = 0; i < tail; ++i) {
        float uc = med3(__builtin_fmaf(cur[i], U_SCALE, U_BIAS), 0.0f, UCMAXF);
        int   ci = (int)uc;
        float xi = __builtin_fmaf(2.0f, uc - (float)ci, -1.0f);
        float x2 = xi * xi;
        int  cib = tb + (ci << 4) - 144;
        STEP_BODY(xi, x2, cib, 0);
    }
    // ---- epilogue: drain and finish the last accurate combine ----
    asm volatile("s_waitcnt lgkmcnt(0)" ::: "memory");
    __builtin_amdgcn_sched_barrier(0);
    {
        float e  = med3(za, 0.0f, NSM1F) - kmfp;
        float c0 = e + 1.0f, c1 = e, c2 = e - 1.0f, c3 = e - 2.0f;
        float n01 = c0 * c1, n23 = c2 * c3;
        float w0 = c1 * n23 * (-1.0f / 6.0f), w1 = c0 * n23 * 0.5f;
        float w2 = n01 * c3 * (-0.5f),        w3 = n01 * c2 * (1.0f / 6.0f);
        float l0 = __builtin_fmaf(p0[1], xip, p0[0]);
        float h0 = __builtin_fmaf(p0[3], xip, p0[2]);
        float l3 = __builtin_fmaf(p3[1], xip, p3[0]);
        float h3 = __builtin_fmaf(p3[3], xip, p3[2]);
        float r0 = __builtin_fmaf(h0, xi2p, l0);
        float r3 = __builtin_fmaf(h3, xi2p, l3);
        za = __builtin_fmaf(w0, r0, w1 * r1p) + __builtin_fmaf(w2, r2p, w3 * r3);
    }

    const float z = za;
    if (seg == 0) z255[b] = z;
    else {
        float* p = (node < split) ? (baseA + (size_t)node * 4096)
                                  : (baseB + (size_t)(node - split) * 4096);
        p[b] = z;
    }
}

// ---------------- Tier B combine: drain node bufs (d_out+ws) -> s in ws ----------------
__global__ __launch_bounds__(256) void k_combine(const float* __restrict__ baseA,
                                                 const float* __restrict__ baseB,
                                                 int split, int nn, float dz,
                                                 float* __restrict__ zs) {
    const int b = blockIdx.x * 256 + threadIdx.x;
    float zz = combine_eval(zs[b], nn, dz, baseA, baseB, split, b);
    zs[b] = __builtin_fmaf(zz, S_H, S_LOc);          // denormalized s_511
}

// ---------------- Tier A: fused combine (all node bufs in ws) + head ----------------
__global__ __launch_bounds__(256) void head_combine_A(
    const float* __restrict__ x,  const float* __restrict__ Wx,
    const float* __restrict__ bx, const float* __restrict__ Wy,
    const float* __restrict__ by, const float* __restrict__ ws,
    float* __restrict__ out)
{
    const int lane = threadIdx.x & 63;
    const int wave = threadIdx.x >> 6;
    const int b    = blockIdx.x * 4 + wave;

    float zz = combine_eval(ws[b], 14, DZ14, ws + 4096, ws + 4096, 14, b);
    const float s = __builtin_fmaf(zz, S_H, S_LOc);

    const float C  = 2.8853900817779268f;
    const float u  = x[(size_t)(SEQ - 1) * BATCH + b];
    const float sc = s * C;
    float acc[NOUT];
#pragma unroll
    for (int i = 0; i < NOUT; ++i) acc[i] = 0.0f;
#pragma unroll 4
    for (int k = 0; k < KPL; ++k) {
        const int j = k * 64 + lane;
        float arg = __builtin_fmaf(u, Wx[j] * C, bx[j] * C) + sc;
        float r   = fast_rcp(fast_exp2(arg) + 1.0f);
        float th  = __builtin_fmaf(-2.0f, r, 1.0f);
#pragma unroll
        for (int i = 0; i < NOUT; ++i)
            acc[i] = __builtin_fmaf(Wy[i * HID + j], th, acc[i]);
    }
#pragma unroll
    for (int i = 0; i < NOUT; ++i) acc[i] = wave_sum(acc[i]) + by[i];
    float m = acc[0];
#pragma unroll
    for (int i = 1; i < NOUT; ++i) m = fmaxf(m, acc[i]);
    const float L2E = 1.4426950408889634f;
    float ev[NOUT]; float Z = 0.0f;
#pragma unroll
    for (int i = 0; i < NOUT; ++i) { ev[i] = fast_exp2((acc[i] - m) * L2E); Z += ev[i]; }
    const float rz = fast_rcp(Z);
    if (lane == 0) {
#pragma unroll
        for (int i = 0; i < NOUT; ++i) out[(size_t)b * NOUT + i] = ev[i] * rz;
    }
}

// ---------------- exact scan + head (validated R0; also tier-B head) ----------------
__global__ __launch_bounds__(256) void rnn_scan_exact(
    const float* __restrict__ x,  const float* __restrict__ Wx,
    const float* __restrict__ bx, const float* __restrict__ Wh,
    const float* __restrict__ bh, float* __restrict__ s_out)
{
    const int lane = threadIdx.x & 63;
    const int wave = threadIdx.x >> 6;
    const int b    = blockIdx.x * 4 + wave;
    const float C = 2.8853900817779268f;
    float wxs[KPL], bxs[KPL], whn[KPL];
    float swh = 0.0f;
#pragma unroll
    for (int k = 0; k < KPL; ++k) {
        const int j = k * 64 + lane;
        const float w = Wh[j];
        wxs[k] = Wx[j] * C; bxs[k] = bx[j] * C; whn[k] = -2.0f * w; swh += w;
    }
    swh = wave_sum(swh);
    const float bh0 = bh[0];
    const float K0  = bh0 + swh;
    float s = bh0, u = x[b];
    for (int t = 0; t < SEQ - 1; ++t) {
        float u_next = x[(size_t)(t + 1) * BATCH + b];
        const float sc = s * C;
        float p = 0.0f;
#pragma unroll
        for (int k = 0; k < KPL; ++k) {
            float arg = __builtin_fmaf(u, wxs[k], bxs[k]) + sc;
            float r   = fast_rcp(fast_exp2(arg) + 1.0f);
            p = __builtin_fmaf(whn[k], r, p);
        }
        s = K0 + wave_sum(p);
        u = u_next;
    }
    if (lane == 0) s_out[b] = s;
}

__global__ __launch_bounds__(256) void rnn_head_exact(
    const float* __restrict__ x,  const float* __restrict__ Wx,
    const float* __restrict__ bx, const float* __restrict__ Wy,
    const float* __restrict__ by, const float* __restrict__ s_in,
    float* __restrict__ out)
{
    const int lane = threadIdx.x & 63;
    const int wave = threadIdx.x >> 6;
    const int b    = blockIdx.x * 4 + wave;
    const float C  = 2.8853900817779268f;
    const float s  = s_in[b];
    const float u  = x[(size_t)(SEQ - 1) * BATCH + b];
    const float sc = s * C;
    float acc[NOUT];
#pragma unroll
    for (int i = 0; i < NOUT; ++i) acc[i] = 0.0f;
#pragma unroll 4
    for (int k = 0; k < KPL; ++k) {
        const int j = k * 64 + lane;
        float arg = __builtin_fmaf(u, Wx[j] * C, bx[j] * C) + sc;
        float r   = fast_rcp(fast_exp2(arg) + 1.0f);
        float th  = __builtin_fmaf(-2.0f, r, 1.0f);
#pragma unroll
        for (int i = 0; i < NOUT; ++i)
            acc[i] = __builtin_fmaf(Wy[i * HID + j], th, acc[i]);
    }
#pragma unroll
    for (int i = 0; i < NOUT; ++i) acc[i] = wave_sum(acc[i]) + by[i];
    float m = acc[0];
#pragma unroll
    for (int i = 1; i < NOUT; ++i) m = fmaxf(m, acc[i]);
    const float L2E = 1.4426950408889634f;
    float ev[NOUT]; float Z = 0.0f;
#pragma unroll
    for (int i = 0; i < NOUT; ++i) { ev[i] = fast_exp2((acc[i] - m) * L2E); Z += ev[i]; }
    const float rz = fast_rcp(Z);
    if (lane == 0) {
#pragma unroll
        for (int i = 0; i < NOUT; ++i) out[(size_t)b * NOUT + i] = ev[i] * rz;
    }
}

extern "C" void kernel_launch(void* const* d_in, const int* in_sizes, int n_in,
                              void* d_out, int out_size, void* d_ws, size_t ws_size,
                              hipStream_t stream)
{
    const float* x  = (const float*)d_in[0];
    const float* Wx = (const float*)d_in[1];
    const float* bx = (const float*)d_in[2];
    const float* Wh = (const float*)d_in[3];
    const float* bh = (const float*)d_in[4];
    const float* Wy = (const float*)d_in[5];
    const float* by = (const float*)d_in[6];
    float* out = (float*)d_out;
    float* wf  = (float*)d_ws;

    if (ws_size >= (size_t)WSA_FLOATS * sizeof(float)) {
        // Tier A: 14 nodes, all node bufs in ws; 3 launches
        k_coef<<<NS, 256, 0, stream>>>(Wx, bx, Wh, bh, out);
        k_scan_seg<<<16 + 14 * 16, 256, 0, stream>>>(x, bh, out, wf,
                                                     wf + 4096, wf + 4096, 14, DZ14);
        head_combine_A<<<BATCH / 4, 256, 0, stream>>>(x, Wx, bx, Wy, by, wf, out);
    } else if (ws_size >= (size_t)WSB_FLOATS * sizeof(float)) {
        // Tier B: 9 nodes (5 bufs borrow d_out, drained by k_combine before head)
        k_coef<<<NS, 256, 0, stream>>>(Wx, bx, Wh, bh, out);
        k_scan_seg<<<16 + 9 * 16, 256, 0, stream>>>(x, bh, out, wf,
                                                    out + TABLE_FLOATS, wf + 4096, 5, DZ9);
        k_combine<<<16, 256, 0, stream>>>(out + TABLE_FLOATS, wf + 4096, 5, 9, DZ9, wf);
        rnn_head_exact<<<BATCH / 4, 256, 0, stream>>>(x, Wx, bx, Wy, by, wf, out);
    } else {
        rnn_scan_exact<<<BATCH / 4, 256, 0, stream>>>(x, Wx, bx, Wh, bh, wf);
        rnn_head_exact<<<BATCH / 4, 256, 0, stream>>>(x, Wx, bx, Wy, by, wf, out);
    }
}